// Round 10
// baseline (79.822 us; speedup 1.0000x reference)
//
#include <hip/hip_runtime.h>
#include <hip/hip_fp16.h>

// Depthwise 3D Gaussian conv (1,3,160,160,160) fp32, K=25, radius=12.
// Separable. Round 10: fused W+H per (c,d)-plane (both convs are
// within-plane!), built ONLY from r7-proven access patterns:
//   stage  = conv_w's transposed coalesced stage (fp16, h-pairs)
//   Wphase = conv_w's pk-over-h-pairs sliding window  -> WH in LDS
//   Hphase = conv_h's pk-over-w-pairs sliding window  -> fp16 global
// 45 KB LDS -> 3 blocks/CU (r5 died at 2), no per-lane row-scatter (r8).
// D pass unchanged (r9).

#define NV 160
constexpr int KS    = 25;
constexpr int RAD   = 12;
constexpr int PLANE = NV * NV;        // 25600
constexpr int VOL   = NV * NV * NV;   // 4,096,000
constexpr int TOT   = 3 * VOL;        // 12,288,000
constexpr int ROWS  = NV + 2 * RAD;   // 184

// fused_wh geometry
constexpr int HC    = 40;             // h outputs per block
constexpr int XHP   = 32;             // h-pairs staged (64 rows = 40+24)
constexpr int XP    = 33;             // X pitch (32 hp + 1)
constexpr int WHR   = 64;             // WH rows (h)
constexpr int WHPIT = 81;             // WH pitch in half2 (80 wp + 1)

// D-pass geometry (r9)
constexpr int QP    = 9;              // float4 pitch
constexpr int OPT4  = 5;
constexpr int WIN4  = OPT4 + KS - 1;  // 29

__device__ __forceinline__ void pk(float2& a, float2 g, float2 v) {
    asm("v_pk_fma_f32 %0, %1, %2, %0" : "+v"(a) : "v"(g), "v"(v));
}

// Recover g1[t] from k3: g1[t] = g3[t,12,12] / cbrt(g3[12,12,12])^2 (exact).
__device__ __forceinline__ void load_g(const float* __restrict__ k3, float* g) {
    float c   = k3[12 * 625 + 312];          // g1[12]^3
    float g12 = cbrtf(c);
    float inv = 1.0f / (g12 * g12);
#pragma unroll
    for (int t = 0; t < KS; ++t) g[t] = k3[t * 625 + 312] * inv;
}

// unpack 8 halfs (uint4) -> two float4
__device__ __forceinline__ void unpack8(uint4 raw, float4& lo, float4& hi) {
    __half2* hp = (__half2*)&raw;
    float2 a = __half22float2(hp[0]);
    float2 b = __half22float2(hp[1]);
    float2 c = __half22float2(hp[2]);
    float2 d = __half22float2(hp[3]);
    lo = make_float4(a.x, a.y, b.x, b.y);
    hi = make_float4(c.x, c.y, d.x, d.y);
}

// ---------------- fused W+H: f32 in -> f16 out ----------------
__global__ __launch_bounds__(320, 2) void fused_wh(const float* __restrict__ in,
                                                   __half* __restrict__ out,
                                                   const float* __restrict__ k3) {
    __shared__ __half2 X[ROWS][XP];          // 184*33*4 = 24288 B
    __shared__ __half2 WH[WHR][WHPIT];       // 64*81*4  = 20736 B
    float gs[KS];
    load_g(k3, gs);
    float2 g2[KS];
#pragma unroll
    for (int t = 0; t < KS; ++t) g2[t] = make_float2(gs[t], gs[t]);

    int tid = threadIdx.x;
    int b   = blockIdx.x;
    int hc  = b & 3;                   // h-chunk
    int cd  = b >> 2;                  // c*160 + d
    int h0  = hc * HC;
    const float* base = in + (size_t)cd * PLANE;

    // ---- stage: X[wi][hp] = {x[h0-12+2hp][wi-12], x[h0-12+2hp+1][wi-12]} ----
    int lane = tid & 63;               // walks wi (coalesced)
    int g5   = tid >> 6;               // 0..4
#pragma unroll
    for (int k = 0; k < 7; ++k) {
        int hp = g5 + 5 * k;
        if (hp < XHP) {
            int hA = h0 - RAD + 2 * hp;        // even
            const float* rA = base + hA * NV;
#pragma unroll
            for (int s = 0; s < 3; ++s) {
                int wi = s * 64 + lane;
                if (wi < ROWS) {
                    int wv = wi - RAD;
                    float a = 0.f, b2 = 0.f;
                    if (wv >= 0 && wv < NV && hA >= 0 && hA < NV) {
                        a = rA[wv];
                        if (hA + 1 < NV) b2 = rA[NV + wv];
                    }
                    X[wi][hp] = __float22half2_rn(make_float2(a, b2));
                }
            }
        }
    }
    __syncthreads();

    // ---- W phase: 512 tasks = (hp 0..31) x (wc 0..15 chunks of 10 w) ----
    __half* WHh = (__half*)(&WH[0][0]);      // [64][162] halfs
#pragma unroll
    for (int iter = 0; iter < 2; ++iter) {
        int task = iter * 320 + tid;
        if (task < 512) {
            int hp = task & 31;
            int wc = task >> 5;
            float2 acc[10];
#pragma unroll
            for (int j = 0; j < 10; ++j) acc[j] = make_float2(0.f, 0.f);
#pragma unroll
            for (int it = 0; it < 34; ++it) {
                float2 v = __half22float2(X[wc * 10 + it][hp]);
#pragma unroll
                for (int j = 0; j < 10; ++j) {
                    int t = it - j;
                    if (t >= 0 && t < KS) pk(acc[j], g2[t], v);
                }
            }
            int rowA = 2 * hp * 162;
#pragma unroll
            for (int j = 0; j < 10; ++j) {
                int w = wc * 10 + j;
                WHh[rowA + w]       = __float2half_rn(acc[j].x);
                WHh[rowA + 162 + w] = __float2half_rn(acc[j].y);
            }
        }
    }
    __syncthreads();

    // ---- H phase: 320 tasks = (wp 0..79) x (rc 0..3 chunks of 10 h) ----
    int wp = tid % 80;
    int rc = tid / 80;
    float2 acc[10];
#pragma unroll
    for (int j = 0; j < 10; ++j) acc[j] = make_float2(0.f, 0.f);
#pragma unroll
    for (int it = 0; it < 34; ++it) {
        float2 v = __half22float2(WH[rc * 10 + it][wp]);
#pragma unroll
        for (int j = 0; j < 10; ++j) {
            int t = it - j;
            if (t >= 0 && t < KS) pk(acc[j], g2[t], v);
        }
    }
    __half* ob = out + (size_t)cd * PLANE + (size_t)(h0 + rc * 10) * NV + 2 * wp;
#pragma unroll
    for (int j = 0; j < 10; ++j)
        *(__half2*)(ob + j * NV) = __float22half2_rn(acc[j]);
}

// ---------------- D pass: f16 in -> f32 out (r9, proven) ----------------
__global__ __launch_bounds__(256) void conv_d(const __half* __restrict__ in,
                                              float* __restrict__ out,
                                              const float* __restrict__ k3) {
    __shared__ float4 T4[ROWS][QP];
    float gs[KS];
    load_g(k3, gs);
    float2 g2[KS];
#pragma unroll
    for (int t = 0; t < KS; ++t) g2[t] = make_float2(gs[t], gs[t]);

    int tid = threadIdx.x;
    int b   = blockIdx.x;
    int wt  = b % 5;
    int ch  = b / 5;               // c*160 + h
    int c   = ch / NV, h = ch % NV;
    int w0  = wt * 32;
    const __half* base = in + (size_t)c * VOL + h * NV + w0;

    int e = tid & 3, r0 = tid >> 2;
#pragma unroll
    for (int ib = 0; ib < ROWS; ib += 64) {
        int i = ib + r0;
        if (i < ROWS) {
            int d = i - RAD;
            float4 lo = make_float4(0.f, 0.f, 0.f, 0.f), hi = lo;
            if (d >= 0 && d < NV) {
                uint4 raw = *(const uint4*)(base + (size_t)d * PLANE + 8 * e);
                unpack8(raw, lo, hi);
            }
            T4[i][2 * e]     = lo;
            T4[i][2 * e + 1] = hi;
        }
    }
    __syncthreads();

    int wq = tid & 7, ct = tid >> 3;
    int db = ct * OPT4;
    float2 alo[OPT4], ahi[OPT4];
#pragma unroll
    for (int j = 0; j < OPT4; ++j) { alo[j] = make_float2(0.f, 0.f); ahi[j] = alo[j]; }
#pragma unroll
    for (int it = 0; it < WIN4; ++it) {
        float4 v = T4[db + it][wq];
        float2 vlo = make_float2(v.x, v.y);
        float2 vhi = make_float2(v.z, v.w);
#pragma unroll
        for (int j = 0; j < OPT4; ++j) {
            int t = it - j;
            if (t >= 0 && t < KS) { pk(alo[j], g2[t], vlo); pk(ahi[j], g2[t], vhi); }
        }
    }
    float* ob = out + (size_t)c * VOL + h * NV + w0 + 4 * wq;
#pragma unroll
    for (int j = 0; j < OPT4; ++j)
        *(float4*)(ob + (size_t)(db + j) * PLANE) =
            make_float4(alo[j].x, alo[j].y, ahi[j].x, ahi[j].y);
}

// Fallback (only if ws too small): direct 25^3-tap depthwise conv.
__global__ __launch_bounds__(256) void conv3d_direct(const float* __restrict__ x,
                                                     const float* __restrict__ k3,
                                                     float* __restrict__ out) {
    int idx = blockIdx.x * 256 + threadIdx.x;
    if (idx >= TOT) return;
    int w = idx % NV;
    int t = idx / NV;
    int h = t % NV; t /= NV;
    int d = t % NV;
    int c = t / NV;
    const float* kc = k3 + c * (KS * KS * KS);
    float acc = 0.f;
    for (int i = 0; i < KS; ++i) {
        int dd = d + i - RAD;
        if (dd < 0 || dd >= NV) continue;
        for (int j = 0; j < KS; ++j) {
            int hh = h + j - RAD;
            if (hh < 0 || hh >= NV) continue;
            const float* xr = x + (c * NV + dd) * NV * NV + hh * NV + (w - RAD);
            const float* kr = kc + (i * KS + j) * KS;
            int k0 = (RAD - w) > 0 ? (RAD - w) : 0;
            int k1 = (NV + RAD - w) < KS ? (NV + RAD - w) : KS;
            for (int k = k0; k < k1; ++k) acc += kr[k] * xr[k];
        }
    }
    out[idx] = acc;
}

extern "C" void kernel_launch(void* const* d_in, const int* in_sizes, int n_in,
                              void* d_out, int out_size, void* d_ws, size_t ws_size,
                              hipStream_t stream) {
    const float* x  = (const float*)d_in[0];
    const float* k3 = (const float*)d_in[1];
    float* out = (float*)d_out;

    if (ws_size >= (size_t)TOT * sizeof(__half)) {
        __half* tmpA = (__half*)d_ws;
        fused_wh<<<480 * 4, 320, 0, stream>>>(x, tmpA, k3);  // x -> tmpA (W+H)
        conv_d<<<2400, 256, 0, stream>>>(tmpA, out, k3);     // tmpA -> out (D)
    } else {
        conv3d_direct<<<(TOT + 255) / 256, 256, 0, stream>>>(x, k3, out);
    }
}

// Round 11
// 55.340 us; speedup vs baseline: 1.4424x; 1.4424x over previous
//
#include <hip/hip_runtime.h>
#include <hip/hip_fp16.h>

// Depthwise 3D Gaussian conv (1,3,160,160,160) fp32, K=25, radius=12.
// Separable -> three 1-D passes, fp16 intermediates (r7/r9 lineage).
// Round 11: H and D passes restructured to full-w x 80-row tiles:
//   - stage is a LINEAR uint4 copy (H: fully contiguous 33KB span;
//     D: 320B per d-row) -> coalesced, low MSHR pressure
//   - 34.9 KB LDS -> 4 blocks/CU, 20 waves/CU
// W pass unchanged from r9. Fusion abandoned (r3/r5/r8/r10 all lost:
// phase-serialized fused blocks can't beat high-residency streaming).

#define NV 160
constexpr int KS    = 25;
constexpr int RAD   = 12;
constexpr int PLANE = NV * NV;        // 25600
constexpr int VOL   = NV * NV * NV;   // 4,096,000
constexpr int TOT   = 3 * VOL;        // 12,288,000
constexpr int ROWS  = NV + 2 * RAD;   // 184

// W-pass geometry (r9)
constexpr int PITCH = 17;             // float2 pitch
constexpr int OPT   = 10;
constexpr int WIN   = OPT + KS - 1;   // 34
constexpr int OROW  = 168;            // output-staging row pitch (halfs)

// H/D-pass geometry (full-w tiles)
constexpr int HC2   = 80;             // outputs per block along conv axis
constexpr int TR    = HC2 + 2 * RAD;  // 104 tile rows
constexpr int TP2   = 84;             // half2 pitch (80 + 4, 16B-aligned)
constexpr int NTASK = TR * 20;        // 2080 stage tasks (16B each)

__device__ __forceinline__ void pk(float2& a, float2 g, float2 v) {
    asm("v_pk_fma_f32 %0, %1, %2, %0" : "+v"(a) : "v"(g), "v"(v));
}

// Recover g1[t] from k3: g1[t] = g3[t,12,12] / cbrt(g3[12,12,12])^2 (exact).
__device__ __forceinline__ void load_g(const float* __restrict__ k3, float* g) {
    float c   = k3[12 * 625 + 312];          // g1[12]^3
    float g12 = cbrtf(c);
    float inv = 1.0f / (g12 * g12);
#pragma unroll
    for (int t = 0; t < KS; ++t) g[t] = k3[t * 625 + 312] * inv;
}

// ---------------- W pass: f32 in -> f16 out (r9, proven) ----------------
__global__ __launch_bounds__(256) void conv_w(const float* __restrict__ in,
                                              __half* __restrict__ out,
                                              const float* __restrict__ k3) {
    __shared__ float2 T[ROWS][PITCH];        // 25024 B (reused as out-stage)
    float gs[KS];
    load_g(k3, gs);
    float2 g2[KS];
#pragma unroll
    for (int t = 0; t < KS; ++t) g2[t] = make_float2(gs[t], gs[t]);

    int tid = threadIdx.x;
    int b   = blockIdx.x;
    int ht  = b % 5;
    int cd  = b / 5;               // c*160 + d
    int h0  = ht * 32;
    const float* base = in + (size_t)cd * PLANE;

    // stage transposed: T[wi][hp] = {x[h0+2hp][wi-12], x[h0+2hp+1][wi-12]}
    int wl = tid & 31, hq = tid >> 5;        // wl 0..31, hq 0..7
#pragma unroll
    for (int hh = 0; hh < 2; ++hh) {
        int hp = hq + hh * 8;                // 0..15
        const float* r0 = base + (h0 + 2 * hp) * NV;
#pragma unroll
        for (int ib = 0; ib < ROWS; ib += 32) {
            int i = ib + wl;
            if (i < ROWS) {
                int wv = i - RAD;
                float a = 0.f, bb = 0.f;
                if (wv >= 0 && wv < NV) { a = r0[wv]; bb = r0[NV + wv]; }
                T[i][hp] = make_float2(a, bb);
            }
        }
    }
    __syncthreads();

    int p  = tid & 15;             // h-pair
    int ct = tid >> 4;             // 0..15
    int wb = ct * OPT;
    float2 acc[OPT];
#pragma unroll
    for (int j = 0; j < OPT; ++j) acc[j] = make_float2(0.f, 0.f);
#pragma unroll
    for (int it = 0; it < WIN; ++it) {
        float2 v = T[wb + it][p];
#pragma unroll
        for (int j = 0; j < OPT; ++j) {
            int t = it - j;
            if (t >= 0 && t < KS) pk(acc[j], g2[t], v);
        }
    }

    // coalesced store epilogue: stage 32x160 halfs (pitch 168) in LDS
    __syncthreads();
    __half* Ost = (__half*)(&T[0][0]);       // 32*336 = 10752 B <= 25024
#pragma unroll
    for (int j = 0; j < OPT; ++j) {
        Ost[(2 * p)     * OROW + wb + j] = __float2half_rn(acc[j].x);
        Ost[(2 * p + 1) * OROW + wb + j] = __float2half_rn(acc[j].y);
    }
    __syncthreads();
    __half* ob = out + (size_t)cd * PLANE + (size_t)h0 * NV;
#pragma unroll
    for (int it = 0; it < 3; ++it) {
        int task = it * 256 + tid;           // 640 = 32 rows x 20 chunks
        if (task < 640) {
            int chunk = task % 20, row = task / 20;
            uint4 v = *(const uint4*)(Ost + row * OROW + 8 * chunk);
            *(uint4*)(ob + (size_t)row * NV + 8 * chunk) = v;
        }
    }
}

// ---------------- H pass: f16 in -> f16 out (full-w tile) ----------------
__global__ __launch_bounds__(320) void conv_h(const __half* __restrict__ in,
                                              __half* __restrict__ out,
                                              const float* __restrict__ k3) {
    __shared__ __half2 T[TR][TP2];           // 104*84*4 = 34944 B
    float gs[KS];
    load_g(k3, gs);
    float2 g2[KS];
#pragma unroll
    for (int t = 0; t < KS; ++t) g2[t] = make_float2(gs[t], gs[t]);

    int tid = threadIdx.x;
    int b   = blockIdx.x;
    int hh  = b & 1;
    int cd  = b >> 1;              // c*160 + d
    int h0  = hh * HC2;
    const __half* base = in + (size_t)cd * PLANE;

    // stage: linear 16B tasks over [104 rows][20 chunks] (rows contiguous!)
#pragma unroll
    for (int it = 0; it < 7; ++it) {
        int task = it * 320 + tid;
        if (task < NTASK) {
            int r = task / 20, k = task % 20;
            int hg = h0 - RAD + r;
            uint4 v = make_uint4(0u, 0u, 0u, 0u);
            if (hg >= 0 && hg < NV)
                v = *(const uint4*)(base + hg * NV + 8 * k);
            *(uint4*)(&T[r][4 * k]) = v;
        }
    }
    __syncthreads();

    int wp = tid % 80, oc = tid / 80;        // wp 0..79, oc 0..3
#pragma unroll
    for (int hv = 0; hv < 2; ++hv) {
        int rb = (oc + 4 * hv) * OPT;        // 0..70
        float2 acc[OPT];
#pragma unroll
        for (int j = 0; j < OPT; ++j) acc[j] = make_float2(0.f, 0.f);
#pragma unroll
        for (int it = 0; it < WIN; ++it) {
            float2 v = __half22float2(T[rb + it][wp]);
#pragma unroll
            for (int j = 0; j < OPT; ++j) {
                int t = it - j;
                if (t >= 0 && t < KS) pk(acc[j], g2[t], v);
            }
        }
        __half* op = out + (size_t)cd * PLANE + (size_t)(h0 + rb) * NV + 2 * wp;
#pragma unroll
        for (int j = 0; j < OPT; ++j)
            *(__half2*)(op + j * NV) = __float22half2_rn(acc[j]);
    }
}

// ---------------- D pass: f16 in -> f32 out (full-w tile) ----------------
__global__ __launch_bounds__(320) void conv_d(const __half* __restrict__ in,
                                              float* __restrict__ out,
                                              const float* __restrict__ k3) {
    __shared__ __half2 T[TR][TP2];           // 34944 B
    float gs[KS];
    load_g(k3, gs);
    float2 g2[KS];
#pragma unroll
    for (int t = 0; t < KS; ++t) g2[t] = make_float2(gs[t], gs[t]);

    int tid = threadIdx.x;
    int b   = blockIdx.x;
    int dh  = b & 1;
    int ch  = b >> 1;              // c*160 + h
    int c   = ch / NV, h = ch % NV;
    int d0  = dh * HC2;
    const __half* base = in + (size_t)c * VOL + h * NV;

    // stage: [104 d-rows][20 chunks], 320B coalesced per row
#pragma unroll
    for (int it = 0; it < 7; ++it) {
        int task = it * 320 + tid;
        if (task < NTASK) {
            int r = task / 20, k = task % 20;
            int dg = d0 - RAD + r;
            uint4 v = make_uint4(0u, 0u, 0u, 0u);
            if (dg >= 0 && dg < NV)
                v = *(const uint4*)(base + (size_t)dg * PLANE + 8 * k);
            *(uint4*)(&T[r][4 * k]) = v;
        }
    }
    __syncthreads();

    int wp = tid % 80, oc = tid / 80;
#pragma unroll
    for (int hv = 0; hv < 2; ++hv) {
        int rb = (oc + 4 * hv) * OPT;        // 0..70
        float2 acc[OPT];
#pragma unroll
        for (int j = 0; j < OPT; ++j) acc[j] = make_float2(0.f, 0.f);
#pragma unroll
        for (int it = 0; it < WIN; ++it) {
            float2 v = __half22float2(T[rb + it][wp]);
#pragma unroll
            for (int j = 0; j < OPT; ++j) {
                int t = it - j;
                if (t >= 0 && t < KS) pk(acc[j], g2[t], v);
            }
        }
        float* op = out + (size_t)c * VOL + h * NV + 2 * wp;
#pragma unroll
        for (int j = 0; j < OPT; ++j)
            *(float2*)(op + (size_t)(d0 + rb + j) * PLANE) = acc[j];
    }
}

// Fallback (only if ws too small): direct 25^3-tap depthwise conv.
__global__ __launch_bounds__(256) void conv3d_direct(const float* __restrict__ x,
                                                     const float* __restrict__ k3,
                                                     float* __restrict__ out) {
    int idx = blockIdx.x * 256 + threadIdx.x;
    if (idx >= TOT) return;
    int w = idx % NV;
    int t = idx / NV;
    int h = t % NV; t /= NV;
    int d = t % NV;
    int c = t / NV;
    const float* kc = k3 + c * (KS * KS * KS);
    float acc = 0.f;
    for (int i = 0; i < KS; ++i) {
        int dd = d + i - RAD;
        if (dd < 0 || dd >= NV) continue;
        for (int j = 0; j < KS; ++j) {
            int hh = h + j - RAD;
            if (hh < 0 || hh >= NV) continue;
            const float* xr = x + (c * NV + dd) * NV * NV + hh * NV + (w - RAD);
            const float* kr = kc + (i * KS + j) * KS;
            int k0 = (RAD - w) > 0 ? (RAD - w) : 0;
            int k1 = (NV + RAD - w) < KS ? (NV + RAD - w) : KS;
            for (int k = k0; k < k1; ++k) acc += kr[k] * xr[k];
        }
    }
    out[idx] = acc;
}

extern "C" void kernel_launch(void* const* d_in, const int* in_sizes, int n_in,
                              void* d_out, int out_size, void* d_ws, size_t ws_size,
                              hipStream_t stream) {
    const float* x  = (const float*)d_in[0];
    const float* k3 = (const float*)d_in[1];
    float* out = (float*)d_out;

    if (ws_size >= (size_t)TOT * 2 * sizeof(__half)) {
        __half* tmpA = (__half*)d_ws;
        __half* tmpB = tmpA + TOT;
        conv_w<<<2400, 256, 0, stream>>>(x, tmpA, k3);        // f32 -> f16 (W)
        conv_h<<<480 * 2, 320, 0, stream>>>(tmpA, tmpB, k3);  // f16 -> f16 (H)
        conv_d<<<480 * 2, 320, 0, stream>>>(tmpB, out, k3);   // f16 -> f32 (D)
    } else {
        conv3d_direct<<<(TOT + 255) / 256, 256, 0, stream>>>(x, k3, out);
    }
}